// Round 1
// baseline (790.838 us; speedup 1.0000x reference)
//
#include <hip/hip_runtime.h>

#define N_ROWS 100000
#define DM 256
#define NS 512

typedef __attribute__((ext_vector_type(8))) short short8;
typedef __attribute__((ext_vector_type(4))) float floatx4;

__device__ __forceinline__ unsigned short f2bf(float x) {
  unsigned int u = __float_as_uint(x);
  u += 0x7fff + ((u >> 16) & 1);   // round-to-nearest-even bf16
  return (unsigned short)(u >> 16);
}
__device__ __forceinline__ float bf2f(unsigned short h) {
  return __uint_as_float(((unsigned int)h) << 16);
}

// ---------------------------------------------------------------------------
// Prep: split each memory into hi/lo bf16 (row-major [512][256]) plus a
// transposed hi copy [256][512] for the PV phase. ws layout per memory:
//   [0]       Mh  512*256
//   [131072]  Ml  512*256
//   [262144]  Mt  256*512   (Mt[d][slot] = Mh[slot][d])
// ---------------------------------------------------------------------------
__global__ __launch_bounds__(256) void prep_split(const float* __restrict__ mA,
                                                  const float* __restrict__ mS,
                                                  unsigned short* __restrict__ ws) {
  const int mem = blockIdx.y;
  const float* M = mem ? mS : mA;
  unsigned short* base = ws + (size_t)mem * 3 * (NS * DM);
  const int t = blockIdx.x * 256 + threadIdx.x;  // grid.x = 512 -> 131072 threads
  const float x = M[t];
  const unsigned short h = f2bf(x);
  const unsigned short l = f2bf(x - bf2f(h));
  base[t] = h;
  base[NS * DM + t] = l;
  const int row = t >> 8;        // slot
  const int col = t & (DM - 1);  // d
  base[2 * NS * DM + col * NS + row] = h;
}

// ---------------------------------------------------------------------------
// Main fused kernel. One block = 4 waves = 64 query rows, one memory.
// Wave w: rows (w&1)*32..+31, slot quarter wq = w>>1 (slots wq*128 + sc*256).
// Phase 1: S = Q*M^T via split-bf16 (3 MFMAs), S in C-frags (128 VGPR/lane).
// Softmax: in-lane + shfl(l&15) + LDS cross-wave-pair reduction.
// Phase 2: O^T = Mt * P^T; P produced per-32-slot chunk into LDS.
// ---------------------------------------------------------------------------
__global__ __launch_bounds__(256, 2) void attn_main(
    const float* __restrict__ q,
    const unsigned short* __restrict__ ws,
    float* __restrict__ out) {
  constexpr int PITCH = 40;  // bf16 elements per LDS row (32 data + 8 pad)

  __shared__ unsigned short MhS[256 * PITCH];
  __shared__ unsigned short MlS[256 * PITCH];
  __shared__ unsigned short QhS[64 * PITCH];
  __shared__ unsigned short QlS[64 * PITCH];
  __shared__ unsigned short MtS[256 * PITCH];
  __shared__ unsigned short PS[64 * PITCH];
  __shared__ float redmax[4][64];
  __shared__ float redsum[4][64];

  const int tid = threadIdx.x;
  const int w   = tid >> 6;
  const int l   = tid & 63;
  const int l15 = l & 15;
  const int lq  = l >> 4;
  const int mem = blockIdx.y;
  const int qbase = blockIdx.x * 64;

  const unsigned short* Mh = ws + (size_t)mem * 3 * (NS * DM);
  const unsigned short* Ml = Mh + NS * DM;
  const unsigned short* Mt = Mh + 2 * NS * DM;
  float* outM = out + (size_t)mem * N_ROWS * (2 * DM);

  // ---- copy q -> out[:, 0:256] (coalesced float4)
  #pragma unroll
  for (int u = 0; u < 16; ++u) {
    const int idx = u * 256 + tid;
    const int row = idx >> 6, c4 = idx & 63;
    const int grow = qbase + row;
    if (grow < N_ROWS) {
      const float4 v = *(const float4*)(q + (size_t)grow * DM + c4 * 4);
      *(float4*)(outM + (size_t)grow * (2 * DM) + c4 * 4) = v;
    }
  }

  const int wrow = (w & 1) * 32;
  const int wq   = w >> 1;

  floatx4 acc[2][16];
  #pragma unroll
  for (int rt = 0; rt < 2; ++rt)
    #pragma unroll
    for (int j = 0; j < 16; ++j) acc[rt][j] = (floatx4){0.f, 0.f, 0.f, 0.f};

  // ================= Phase 1: scores =================
  for (int kc = 0; kc < 8; ++kc) {
    // stage Q[64 rows][32 k] -> split into QhS/QlS
    {
      const int row = tid >> 2, o = tid & 3;
      int grow = qbase + row;
      if (grow >= N_ROWS) grow = N_ROWS - 1;  // clamp; garbage rows never stored
      const float* src = q + (size_t)grow * DM + kc * 32 + o * 8;
      const float4 a = *(const float4*)src;
      const float4 b = *(const float4*)(src + 4);
      const float xs[8] = {a.x, a.y, a.z, a.w, b.x, b.y, b.z, b.w};
      union { short8 v; unsigned short s[8]; } uh, ul;
      #pragma unroll
      for (int e = 0; e < 8; ++e) {
        const unsigned short hh = f2bf(xs[e]);
        uh.s[e] = hh;
        ul.s[e] = f2bf(xs[e] - bf2f(hh));
      }
      *(short8*)(&QhS[row * PITCH + o * 8]) = uh.v;
      *(short8*)(&QlS[row * PITCH + o * 8]) = ul.v;
    }
    #pragma unroll
    for (int sc = 0; sc < 2; ++sc) {
      // stage M half: slots sc*256..+255, cols kc*32..+31 (hi & lo)
      #pragma unroll
      for (int u = 0; u < 4; ++u) {
        const int i = u * 256 + tid;
        const int srow = i >> 2, o = i & 3;
        const size_t goff = (size_t)(sc * 256 + srow) * DM + kc * 32 + o * 8;
        *(short8*)(&MhS[srow * PITCH + o * 8]) = *(const short8*)(Mh + goff);
        *(short8*)(&MlS[srow * PITCH + o * 8]) = *(const short8*)(Ml + goff);
      }
      __syncthreads();
      short8 ah[2], al[2];
      #pragma unroll
      for (int rt = 0; rt < 2; ++rt) {
        const int row = wrow + rt * 16 + l15;
        ah[rt] = *(const short8*)(&QhS[row * PITCH + lq * 8]);
        al[rt] = *(const short8*)(&QlS[row * PITCH + lq * 8]);
      }
      #pragma unroll
      for (int nt = 0; nt < 8; ++nt) {
        const int srow = wq * 128 + nt * 16 + l15;
        const short8 bh = *(const short8*)(&MhS[srow * PITCH + lq * 8]);
        const short8 bl = *(const short8*)(&MlS[srow * PITCH + lq * 8]);
        #pragma unroll
        for (int rt = 0; rt < 2; ++rt) {
          floatx4 c = acc[rt][sc * 8 + nt];
          c = __builtin_amdgcn_mfma_f32_16x16x32_bf16(ah[rt], bh, c, 0, 0, 0);
          c = __builtin_amdgcn_mfma_f32_16x16x32_bf16(ah[rt], bl, c, 0, 0, 0);
          c = __builtin_amdgcn_mfma_f32_16x16x32_bf16(al[rt], bh, c, 0, 0, 0);
          acc[rt][sc * 8 + nt] = c;
        }
      }
      __syncthreads();
    }
  }

  // ================= Softmax (row-wise over 512 slots) =================
  float rowm[2][4], rowinv[2][4];
  {
    float pm[2][4];
    #pragma unroll
    for (int rt = 0; rt < 2; ++rt)
      #pragma unroll
      for (int r = 0; r < 4; ++r) {
        float m = -1e30f;
        #pragma unroll
        for (int j = 0; j < 16; ++j) m = fmaxf(m, acc[rt][j][r]);
        pm[rt][r] = m;
      }
    #pragma unroll
    for (int off = 1; off <= 8; off <<= 1)
      #pragma unroll
      for (int rt = 0; rt < 2; ++rt)
        #pragma unroll
        for (int r = 0; r < 4; ++r)
          pm[rt][r] = fmaxf(pm[rt][r], __shfl_xor(pm[rt][r], off));
    if (l15 == 0) {
      #pragma unroll
      for (int rt = 0; rt < 2; ++rt)
        #pragma unroll
        for (int r = 0; r < 4; ++r)
          redmax[w][wrow + rt * 16 + lq * 4 + r] = pm[rt][r];
    }
    __syncthreads();
    #pragma unroll
    for (int rt = 0; rt < 2; ++rt)
      #pragma unroll
      for (int r = 0; r < 4; ++r) {
        const int row = wrow + rt * 16 + lq * 4 + r;
        rowm[rt][r] = fmaxf(redmax[w][row], redmax[w ^ 2][row]);
      }
    float psum[2][4] = {{0.f, 0.f, 0.f, 0.f}, {0.f, 0.f, 0.f, 0.f}};
    #pragma unroll
    for (int rt = 0; rt < 2; ++rt)
      #pragma unroll
      for (int j = 0; j < 16; ++j) {
        floatx4 c = acc[rt][j];
        #pragma unroll
        for (int r = 0; r < 4; ++r) {
          const float e = __expf(c[r] - rowm[rt][r]);
          c[r] = e;
          psum[rt][r] += e;
        }
        acc[rt][j] = c;
      }
    #pragma unroll
    for (int off = 1; off <= 8; off <<= 1)
      #pragma unroll
      for (int rt = 0; rt < 2; ++rt)
        #pragma unroll
        for (int r = 0; r < 4; ++r)
          psum[rt][r] += __shfl_xor(psum[rt][r], off);
    if (l15 == 0) {
      #pragma unroll
      for (int rt = 0; rt < 2; ++rt)
        #pragma unroll
        for (int r = 0; r < 4; ++r)
          redsum[w][wrow + rt * 16 + lq * 4 + r] = psum[rt][r];
    }
    __syncthreads();
    #pragma unroll
    for (int rt = 0; rt < 2; ++rt)
      #pragma unroll
      for (int r = 0; r < 4; ++r) {
        const int row = wrow + rt * 16 + lq * 4 + r;
        rowinv[rt][r] = 1.f / (redsum[w][row] + redsum[w ^ 2][row]);
      }
  }

  // ================= Phase 2: O^T = Mt @ P^T =================
  floatx4 oacc[4][4];
  #pragma unroll
  for (int mt = 0; mt < 4; ++mt)
    #pragma unroll
    for (int nt = 0; nt < 4; ++nt) oacc[mt][nt] = (floatx4){0.f, 0.f, 0.f, 0.f};

  #pragma unroll
  for (int kc2 = 0; kc2 < 16; ++kc2) {  // 32 slots per chunk
    // stage Mt chunk [256 d][32 slots]
    #pragma unroll
    for (int u = 0; u < 4; ++u) {
      const int i = u * 256 + tid;
      const int drow = i >> 2, o = i & 3;
      *(short8*)(&MtS[drow * PITCH + o * 8]) =
          *(const short8*)(Mt + (size_t)drow * NS + kc2 * 32 + o * 8);
    }
    // owning wave-pair writes P chunk (bf16, row-major [64][32])
    if (wq == ((kc2 >> 2) & 1)) {
      const int sc  = kc2 >> 3;
      const int nt0 = (kc2 & 3) * 2;
      #pragma unroll
      for (int nn = 0; nn < 2; ++nn)
        #pragma unroll
        for (int rt = 0; rt < 2; ++rt) {
          const floatx4 c = acc[rt][sc * 8 + nt0 + nn];
          #pragma unroll
          for (int r = 0; r < 4; ++r) {
            const unsigned short pb = f2bf(c[r] * rowinv[rt][r]);
            PS[(wrow + rt * 16 + lq * 4 + r) * PITCH + nn * 16 + l15] = pb;
          }
        }
    }
    __syncthreads();
    short8 bfr[4];
    #pragma unroll
    for (int nt = 0; nt < 4; ++nt)
      bfr[nt] = *(const short8*)(&PS[(nt * 16 + l15) * PITCH + lq * 8]);
    #pragma unroll
    for (int mt = 0; mt < 4; ++mt) {
      const int drow = w * 64 + mt * 16 + l15;
      const short8 a = *(const short8*)(&MtS[drow * PITCH + lq * 8]);
      #pragma unroll
      for (int nt = 0; nt < 4; ++nt)
        oacc[mt][nt] =
            __builtin_amdgcn_mfma_f32_16x16x32_bf16(a, bfr[nt], oacc[mt][nt], 0, 0, 0);
    }
    __syncthreads();
  }

  // store O^T: C-frag rows are d (contiguous per lane -> float4), cols are qrow
  #pragma unroll
  for (int mt = 0; mt < 4; ++mt)
    #pragma unroll
    for (int nt = 0; nt < 4; ++nt) {
      const int grow = qbase + nt * 16 + l15;
      if (grow < N_ROWS) {
        const int d0 = w * 64 + mt * 16 + lq * 4;
        *(floatx4*)(outM + (size_t)grow * (2 * DM) + DM + d0) = oacc[mt][nt];
      }
    }
}

extern "C" void kernel_launch(void* const* d_in, const int* in_sizes, int n_in,
                              void* d_out, int out_size, void* d_ws, size_t ws_size,
                              hipStream_t stream) {
  const float* query = (const float*)d_in[0];
  const float* mA    = (const float*)d_in[1];
  const float* mS    = (const float*)d_in[2];
  float* out = (float*)d_out;
  unsigned short* ws = (unsigned short*)d_ws;  // needs 1.5 MB

  hipLaunchKernelGGL(prep_split, dim3(512, 2), dim3(256), 0, stream, mA, mS, ws);
  hipLaunchKernelGGL(attn_main, dim3((N_ROWS + 63) / 64, 2), dim3(256), 0, stream,
                     query, ws, out);
}